// Round 13
// baseline (324.823 us; speedup 1.0000x reference)
//
#include <hip/hip_runtime.h>
#include <math.h>

// ---------- types ----------
typedef __bf16 bf16x8 __attribute__((ext_vector_type(8)));   // MFMA A/B fragment (4 VGPRs)
typedef short  s16x4  __attribute__((ext_vector_type(4)));   // 16x16x16 MFMA A/B fragment (2 VGPRs)
typedef float  f32x4  __attribute__((ext_vector_type(4)));   // MFMA C/D fragment
typedef short  s16x8  __attribute__((ext_vector_type(8)));   // raw 16B data movement

template <int N> struct ic { static constexpr int value = N; };

__device__ __forceinline__ unsigned short f2bf(float f) {
    unsigned int u = __float_as_uint(f);
    u += 0x7fffu + ((u >> 16) & 1u);   // round-to-nearest-even
    return (unsigned short)(u >> 16);
}

__device__ __forceinline__ unsigned cvt_pk_bf16(float a, float b) {
    unsigned r;
    asm volatile("v_cvt_pk_bf16_f32 %0, %1, %2" : "=v"(r) : "v"(a), "v"(b));
    return r;
}

// 16x16x16 bf16 MFMA via compiler-known builtin (MAI hazard nops inserted; R6 lesson)
__device__ __forceinline__ f32x4 mfma16(s16x4 a, s16x4 b, f32x4 c) {
#if __has_builtin(__builtin_amdgcn_mfma_f32_16x16x16bf16_1k)
    return __builtin_amdgcn_mfma_f32_16x16x16bf16_1k(a, b, c, 0, 0, 0);
#else
    asm volatile("s_nop 3\n\t"
                 "v_mfma_f32_16x16x16_bf16 %0, %1, %2, %0\n\t"
                 "s_nop 7\n\t"
                 "s_nop 7"
                 : "+v"(c) : "v"(a), "v"(b));
    return c;
#endif
}

// exact-equivalent sigmoid form of tanh-gelu: 0.5x(1+tanh(y)) = x * sigmoid(2y)
__device__ __forceinline__ float gelu_tanh(float x) {
    float z = 1.5957691216057308f * (x + 0.044715f * x * x * x);
    return x / (1.0f + __expf(-z));
}

// ---- static-offset ds_read + counted waits (rule 18: sched_barrier after waits) ----
#define DSREAD(dst, addr, IMM) \
    asm volatile("ds_read_b128 %0, %1 offset:%2" : "=v"(dst) : "v"(addr), "i"(IMM))
#define WAITL(N) do { asm volatile("s_waitcnt lgkmcnt(" #N ")" ::: "memory"); \
                      __builtin_amdgcn_sched_barrier(0); } while (0)
#define WAITV(N) do { asm volatile("s_waitcnt vmcnt(" #N ")" ::: "memory"); \
                      __builtin_amdgcn_sched_barrier(0); } while (0)

__device__ __forceinline__ void gload16(const unsigned short* src, unsigned short* ldsdst) {
    __builtin_amdgcn_global_load_lds((const __attribute__((address_space(1))) void*)src,
                                     (__attribute__((address_space(3))) void*)ldsdst, 16, 0, 0);
}

// ---------- transpose + f32->bf16 convert (batched x4) ----------
__global__ __launch_bounds__(256) void tcvt4_kernel(const float* __restrict__ p0,
                                                    const float* __restrict__ p1,
                                                    const float* __restrict__ p2,
                                                    const float* __restrict__ p3,
                                                    unsigned short* __restrict__ out) {
    __shared__ float tile[32][33];
    int z = blockIdx.z;
    const float* in = (z == 0) ? p0 : (z == 1) ? p1 : (z == 2) ? p2 : p3;
    unsigned short* o = out + (size_t)z * 1048576;
    int tx = threadIdx.x, ty = threadIdx.y;           // 32 x 8
    int k0 = blockIdx.y * 32, n0 = blockIdx.x * 32;
#pragma unroll
    for (int s = 0; s < 4; ++s)
        tile[ty + s * 8][tx] = in[(size_t)(k0 + ty + s * 8) * 1024 + n0 + tx];
    __syncthreads();
#pragma unroll
    for (int s = 0; s < 4; ++s)
        o[(size_t)(n0 + ty + s * 8) * 1024 + k0 + tx] = f2bf(tile[tx][ty + s * 8]);
}

// ---------- transpose + convert, generic: in[K][N] f32 -> out[N][K] bf16 ----------
__global__ __launch_bounds__(256) void tcvt_kernel(const float* __restrict__ in,
                                                   unsigned short* __restrict__ out,
                                                   int K, int N) {
    __shared__ float tile[32][33];
    int tx = threadIdx.x, ty = threadIdx.y;
    int k0 = blockIdx.y * 32, n0 = blockIdx.x * 32;
#pragma unroll
    for (int s = 0; s < 4; ++s)
        tile[ty + s * 8][tx] = in[(size_t)(k0 + ty + s * 8) * N + n0 + tx];
    __syncthreads();
#pragma unroll
    for (int s = 0; s < 4; ++s)
        out[(size_t)(n0 + ty + s * 8) * K + k0 + tx] = f2bf(tile[tx][ty + s * 8]);
}

// ---------- layernorm: x[L][1024] f32 -> out bf16 ----------
__global__ __launch_bounds__(256) void ln_kernel(const float* __restrict__ x,
                                                 const float* __restrict__ g,
                                                 const float* __restrict__ b,
                                                 unsigned short* __restrict__ out) {
    int row = blockIdx.x;
    int tid = threadIdx.x;
    float4 v = ((const float4*)(x + (size_t)row * 1024))[tid];
    float s  = v.x + v.y + v.z + v.w;
    float ss = v.x * v.x + v.y * v.y + v.z * v.z + v.w * v.w;
#pragma unroll
    for (int o = 32; o > 0; o >>= 1) { s += __shfl_down(s, o); ss += __shfl_down(ss, o); }
    __shared__ float red[8];
    if ((tid & 63) == 0) { red[(tid >> 6) * 2] = s; red[(tid >> 6) * 2 + 1] = ss; }
    __syncthreads();
    s  = red[0] + red[2] + red[4] + red[6];
    ss = red[1] + red[3] + red[5] + red[7];
    float mean = s * (1.0f / 1024.0f);
    float var  = ss * (1.0f / 1024.0f) - mean * mean;
    float rs   = rsqrtf(var + 1e-5f);
    float4 gv = ((const float4*)g)[tid];
    float4 bv = ((const float4*)b)[tid];
    ushort4 o4;
    o4.x = f2bf((v.x - mean) * rs * gv.x + bv.x);
    o4.y = f2bf((v.y - mean) * rs * gv.y + bv.y);
    o4.z = f2bf((v.z - mean) * rs * gv.z + bv.z);
    o4.w = f2bf((v.w - mean) * rs * gv.w + bv.w);
    ((ushort4*)(out + (size_t)row * 1024))[tid] = o4;
}

// ---------- fused: x2 = sum(4 slabs)+x ;  hbuf = LN(x2) ----------
__global__ __launch_bounds__(256) void reduceln_kernel(const unsigned short* __restrict__ part,
                                                       const float* __restrict__ xin,
                                                       const float* __restrict__ g,
                                                       const float* __restrict__ b,
                                                       float* __restrict__ x2,
                                                       unsigned short* __restrict__ outbf) {
    int row = blockIdx.x;
    int tid = threadIdx.x;
    int i4  = row * 256 + tid;
    float4 r = ((const float4*)xin)[i4];
    float v0 = r.x, v1 = r.y, v2 = r.z, v3 = r.w;
#pragma unroll
    for (int sl = 0; sl < 4; ++sl) {
        ushort4 u = ((const ushort4*)(part + (size_t)sl * 4194304))[i4];
        v0 += __uint_as_float((unsigned)u.x << 16);
        v1 += __uint_as_float((unsigned)u.y << 16);
        v2 += __uint_as_float((unsigned)u.z << 16);
        v3 += __uint_as_float((unsigned)u.w << 16);
    }
    float4 o; o.x = v0; o.y = v1; o.z = v2; o.w = v3;
    ((float4*)x2)[i4] = o;

    float s  = v0 + v1 + v2 + v3;
    float ss = v0 * v0 + v1 * v1 + v2 * v2 + v3 * v3;
#pragma unroll
    for (int off = 32; off > 0; off >>= 1) { s += __shfl_down(s, off); ss += __shfl_down(ss, off); }
    __shared__ float red[8];
    if ((tid & 63) == 0) { red[(tid >> 6) * 2] = s; red[(tid >> 6) * 2 + 1] = ss; }
    __syncthreads();
    s  = red[0] + red[2] + red[4] + red[6];
    ss = red[1] + red[3] + red[5] + red[7];
    float mean = s * (1.0f / 1024.0f);
    float var  = ss * (1.0f / 1024.0f) - mean * mean;
    float rs   = rsqrtf(var + 1e-5f);
    float4 gv = ((const float4*)g)[tid];
    float4 bv = ((const float4*)b)[tid];
    ushort4 o4;
    o4.x = f2bf((v0 - mean) * rs * gv.x + bv.x);
    o4.y = f2bf((v1 - mean) * rs * gv.y + bv.y);
    o4.z = f2bf((v2 - mean) * rs * gv.z + bv.z);
    o4.w = f2bf((v3 - mean) * rs * gv.w + bv.w);
    ((ushort4*)(outbf + (size_t)row * 1024))[tid] = o4;
}

// ---------- transpose V (bf16): qkv v-part -> vt[1024][4096] ----------
__global__ __launch_bounds__(256) void tvt_kernel(const unsigned short* __restrict__ in,
                                                  unsigned short* __restrict__ out) {
    __shared__ unsigned short tile[64][72];
    int t = threadIdx.x;
    int l0 = blockIdx.x * 64, c0 = blockIdx.y * 64;
    int tr = t >> 3, tc = (t & 7) * 8;
#pragma unroll
    for (int s = 0; s < 2; ++s) {
        int r = tr + s * 32;
        s16x8 v = *(const s16x8*)(in + (size_t)(l0 + r) * 3072 + 2048 + c0 + tc);
        *(s16x8*)(&tile[r][tc]) = v;
    }
    __syncthreads();
#pragma unroll
    for (int s = 0; s < 2; ++s) {
        int c = tr + s * 32;
        s16x8 w;
#pragma unroll
        for (int e = 0; e < 8; ++e) w[e] = (short)tile[tc + e][c];
        *(s16x8*)(out + (size_t)(c0 + c) * 4096 + l0 + tc) = w;
    }
}

// ---------- attn staging helpers (chunk-XOR swizzle, rule 21) ----------
__device__ __forceinline__ void stage8(const unsigned short* __restrict__ src_row0, int ld,
                                       unsigned short* ldsdst, int lane) {
    const int r8 = lane >> 3;
    const int c  = (lane & 7) ^ r8;
    const unsigned short* src = src_row0 + (size_t)r8 * ld + c * 8;
    gload16(src, ldsdst);
}

__device__ __forceinline__ bf16x8 ldfrag(const unsigned short* tile, int row, int chunk) {
    return *(const bf16x8*)(tile + (row << 6) + (((chunk ^ row) & 7) << 3));
}

__device__ __forceinline__ s16x4 ldfrag64(const unsigned short* tile, int row, int ch16, int half) {
    return *(const s16x4*)(tile + (row << 6) + (((ch16 ^ row) & 7) << 3) + (half << 2));
}

// ---------- 256x256 pipelined-read 4-phase GEMM, unroll-2 static addressing ----------
// EPI 0: bf16 store; EPI 2: +bias, gelu, bf16; EPI 4: bf16 partial to slab[split]
template <int EPI>
__global__ __launch_bounds__(512, 2) void gemm256_kernel(
        const unsigned short* __restrict__ A, int lda,
        const unsigned short* __restrict__ Bt, int ldb,
        void* __restrict__ Cv, const float* __restrict__ bias,
        int ldc, int NT, int gm, int gn, unsigned long long slab_stride) {
    extern __shared__ unsigned short lds[];
    unsigned short* sA = lds;                  // [2][256*64]
    unsigned short* sB = lds + 2 * 256 * 64;   // [2][256*64]

    const int tid  = threadIdx.x;
    const int wave = tid >> 6, lane = tid & 63;
    const int wr = wave >> 2, wc = wave & 3;       // 2 x 4 wave grid
    const int lg = lane >> 4, l15 = lane & 15;

    const unsigned uA = (unsigned)(size_t)(__attribute__((address_space(3))) void*)sA;
    const unsigned uB = (unsigned)(size_t)(__attribute__((address_space(3))) void*)sB;

    // bijective XCD swizzle (m204)
    const int nwg = gridDim.x;
    const int bid = blockIdx.x;
    const int q8 = nwg >> 3, r8v = nwg & 7;
    const int xcd = bid & 7, loc = bid >> 3;
    const int swz = (xcd < r8v ? xcd * (q8 + 1) : r8v * (q8 + 1) + (xcd - r8v) * q8) + loc;
    const int split = swz / (gm * gn);
    const int rem   = swz % (gm * gn);
    // 2D-banded mapping: 4-wide bcol bands
    const int band = rem / (gm * 4);
    const int r2   = rem % (gm * 4);
    const int brow = (r2 >> 2) << 8;
    const int bcol = (band * 4 + (r2 & 3)) << 8;
    const int kbase = split * (NT << 6);

    // hoisted per-lane stage sources (pre-swizzled global, rule 21) + LDS dests
    const int l8 = lane >> 3;
    const int sc = ((lane & 7) ^ l8) << 3;
    const unsigned short* pA[4];
    const unsigned short* pB[4];
#pragma unroll
    for (int q = 0; q < 4; ++q) {
        pA[q] = A  + (size_t)(brow + q * 64 + wave * 8 + l8) * lda + kbase + sc;
        pB[q] = Bt + (size_t)(bcol + q * 64 + wave * 8 + l8) * ldb + kbase + sc;
    }
    unsigned short* dA = sA + (wave << 9);     // + q*4096 + P*16384 (elements)
    unsigned short* dB = sB + (wave << 9);

    // hoisted ds_read base addresses; all fragment variation is offset-immediate.
    // row&7 == l15&7 for every fragment row, so the XOR-swizzle nibble is constant.
    const unsigned adrA  = uA + ((wr * 128 + l15) << 7) + (((lg ^ l15) & 7) << 4);
    const unsigned adrAk = adrA ^ 64;          // kk=1 chunk (lg+4): swizzle bit flips
    const unsigned adrB  = uB + ((wc * 64 + l15) << 7) + (((lg ^ l15) & 7) << 4);
    const unsigned adrBk = adrB ^ 64;

    f32x4 acc[8][4] = {};
    bf16x8 a0[4][2], a1[4][2], b0[2][2], b1[2][2];
    int koff = 0;                               // scalar k-column for staging

    // prologue: stage t0 -> buf0, t1 -> buf1; wait t0; read a0,b0(t0)
#pragma unroll
    for (int q = 0; q < 4; ++q) gload16(pA[q], dA + q * 4096);
#pragma unroll
    for (int q = 0; q < 4; ++q) gload16(pB[q], dB + q * 4096);
    koff = 64;
#pragma unroll
    for (int q = 0; q < 4; ++q) gload16(pA[q] + koff, dA + q * 4096 + 16384);
#pragma unroll
    for (int q = 0; q < 4; ++q) gload16(pB[q] + koff, dB + q * 4096 + 16384);
    koff = 128;
    WAITV(8);                                  // t0 landed (t1 in flight)
    __builtin_amdgcn_s_barrier();
#pragma unroll
    for (int mi = 0; mi < 4; ++mi) {
        DSREAD(a0[mi][0], adrA,  mi * 2048);
        DSREAD(a0[mi][1], adrAk, mi * 2048);
    }
#pragma unroll
    for (int in = 0; in < 2; ++in) {
        DSREAD(b0[in][0], adrB,  in * 2048);
        DSREAD(b0[in][1], adrBk, in * 2048);
    }

    int t = 0;
    auto body = [&](auto Pc) {
        constexpr int P  = decltype(Pc)::value;
        constexpr int PB = P * 32768;          // ds offset for current buf (bytes)
        constexpr int QB = (P ^ 1) * 32768;    // ds offset for next buf
        constexpr int PE = P * 16384;          // LDS dst offset (elements)

        // ---- PH1: read a1(buf P) | wait a0,b0 | stage A(t+2,q0,q2) | MFMA Q1
#pragma unroll
        for (int mi = 0; mi < 4; ++mi) {
            DSREAD(a1[mi][0], adrA,  PB + 8192 + mi * 2048);
            DSREAD(a1[mi][1], adrAk, PB + 8192 + mi * 2048);
        }
        WAITL(8);
        __builtin_amdgcn_s_barrier();
        if (t + 2 < NT) { gload16(pA[0] + koff, dA + PE); gload16(pA[2] + koff, dA + 8192 + PE); }
        __builtin_amdgcn_s_setprio(1);
#pragma unroll
        for (int kk = 0; kk < 2; ++kk)
#pragma unroll
            for (int im = 0; im < 4; ++im)
#pragma unroll
                for (int in = 0; in < 2; ++in)
                    acc[im][in] = __builtin_amdgcn_mfma_f32_16x16x32_bf16(a0[im][kk], b0[in][kk], acc[im][in], 0, 0, 0);
        __builtin_amdgcn_s_setprio(0);

        // ---- PH2: read b1(buf P) | wait a1 | stage A(t+2,q1,q3) | MFMA Q2
#pragma unroll
        for (int in = 0; in < 2; ++in) {
            DSREAD(b1[in][0], adrB,  PB + 4096 + in * 2048);
            DSREAD(b1[in][1], adrBk, PB + 4096 + in * 2048);
        }
        WAITL(4);
        __builtin_amdgcn_s_barrier();
        if (t + 2 < NT) { gload16(pA[1] + koff, dA + 4096 + PE); gload16(pA[3] + koff, dA + 12288 + PE); }
        __builtin_amdgcn_s_setprio(1);
#pragma unroll
        for (int kk = 0; kk < 2; ++kk)
#pragma unroll
            for (int im = 0; im < 4; ++im)
#pragma unroll
                for (int in = 0; in < 2; ++in)
                    acc[4 + im][in] = __builtin_amdgcn_mfma_f32_16x16x32_bf16(a1[im][kk], b0[in][kk], acc[4 + im][in], 0, 0, 0);
        __builtin_amdgcn_s_setprio(0);

        // ---- PH3: wait b1 | stage B(t+2,q0,q1) | MFMA Q3
        WAITL(0);
        __builtin_amdgcn_s_barrier();
        if (t + 2 < NT) { gload16(pB[0] + koff, dB + PE); gload16(pB[1] + koff, dB + 4096 + PE); }
        __builtin_amdgcn_s_setprio(1);
#pragma unroll
        for (int kk = 0; kk < 2; ++kk)
#pragma unroll
            for (int im = 0; im < 4; ++im)
#pragma unroll
                for (int in = 0; in < 2; ++in)
                    acc[im][2 + in] = __builtin_amdgcn_mfma_f32_16x16x32_bf16(a0[im][kk], b1[in][kk], acc[im][2 + in], 0, 0, 0);
        __builtin_amdgcn_s_setprio(0);

        // ---- PH4: vmcnt fence | barrier | stage B(t+2,q2,q3) | read a0,b0(t+1,buf P^1) | MFMA Q4
        if (t + 1 < NT) {
            if (t + 2 < NT) WAITV(6);
            else            WAITV(0);
        }
        __builtin_amdgcn_s_barrier();
        if (t + 2 < NT) { gload16(pB[2] + koff, dB + 8192 + PE); gload16(pB[3] + koff, dB + 12288 + PE); }
        if (t + 1 < NT) {
#pragma unroll
            for (int mi = 0; mi < 4; ++mi) {
                DSREAD(a0[mi][0], adrA,  QB + mi * 2048);
                DSREAD(a0[mi][1], adrAk, QB + mi * 2048);
            }
#pragma unroll
            for (int in = 0; in < 2; ++in) {
                DSREAD(b0[in][0], adrB,  QB + in * 2048);
                DSREAD(b0[in][1], adrBk, QB + in * 2048);
            }
        }
        __builtin_amdgcn_s_setprio(1);
#pragma unroll
        for (int kk = 0; kk < 2; ++kk)
#pragma unroll
            for (int im = 0; im < 4; ++im)
#pragma unroll
                for (int in = 0; in < 2; ++in)
                    acc[4 + im][2 + in] = __builtin_amdgcn_mfma_f32_16x16x32_bf16(a1[im][kk], b1[in][kk], acc[4 + im][2 + in], 0, 0, 0);
        __builtin_amdgcn_s_setprio(0);
        koff += 64;
    };

    while (t < NT) {
        body(ic<0>{});
        ++t;
        body(ic<1>{});
        ++t;
    }

#pragma unroll
    for (int mi = 0; mi < 8; ++mi)
#pragma unroll
        for (int ni = 0; ni < 4; ++ni)
#pragma unroll
            for (int rr = 0; rr < 4; ++rr) {
                int row = brow + wr * 128 + mi * 16 + lg * 4 + rr;
                int col = bcol + wc * 64 + ni * 16 + l15;
                float v = acc[mi][ni][rr];
                if (EPI == 0) {
                    ((unsigned short*)Cv)[(size_t)row * ldc + col] = f2bf(v);
                } else if (EPI == 2) {
                    v += bias[col];
                    ((unsigned short*)Cv)[(size_t)row * ldc + col] = f2bf(gelu_tanh(v));
                } else {
                    ((unsigned short*)Cv)[slab_stride * split + (size_t)row * ldc + col] = f2bf(v);
                }
            }
}

// ---------- split-K reduce (final): out = sum(4 slabs) + bias + resid ----------
__global__ __launch_bounds__(256) void reduce4_kernel(const unsigned short* __restrict__ part,
                                                      const float* __restrict__ bias,
                                                      const float* __restrict__ resid,
                                                      float* __restrict__ out) {
    int i4 = blockIdx.x * 256 + threadIdx.x;
    float4 r  = ((const float4*)resid)[i4];
    float4 bb = ((const float4*)bias)[i4 & 255];
    float s0 = r.x + bb.x, s1 = r.y + bb.y, s2 = r.z + bb.z, s3 = r.w + bb.w;
#pragma unroll
    for (int s = 0; s < 4; ++s) {
        ushort4 u = ((const ushort4*)(part + (size_t)s * 4194304))[i4];
        s0 += __uint_as_float((unsigned)u.x << 16);
        s1 += __uint_as_float((unsigned)u.y << 16);
        s2 += __uint_as_float((unsigned)u.z << 16);
        s3 += __uint_as_float((unsigned)u.w << 16);
    }
    float4 o; o.x = s0; o.y = s1; o.z = s2; o.w = s3;
    ((float4*)out)[i4] = o;
}

// ---------- band attention v5: no-max softmax (scores bounded), deferred row-sum ----------
__global__ __launch_bounds__(256, 4) void attn5_kernel(const unsigned short* __restrict__ qkv, // [4096][3072]
                                                       const unsigned short* __restrict__ vt,  // [1024][4096]
                                                       const float* __restrict__ rel_emb,      // [258][16]
                                                       unsigned short* __restrict__ outp) {    // [4096][1024]
    const int lid = blockIdx.y * gridDim.x + blockIdx.x;      // 0..1023
    const int rid = (lid & 7) * 128 + (lid >> 3);             // XCD-contiguous
    const int h   = rid >> 6;
    const int n   = rid & 63;

    const int tid  = threadIdx.x;
    const int wv   = tid >> 6;         // 0..3
    const int lane = tid & 63;
    const int lg   = lane >> 4;
    const int l15  = lane & 15;
    const int iq   = wv * 16 + l15;
    const int q0   = n * 64 + wv * 16;

    __shared__ __align__(16) unsigned short sK[2][4096];
    __shared__ __align__(16) unsigned short sV[2][4096];
    __shared__ float sRelF[258];

    bf16x8 qf[2];
    {
        const unsigned short* qrow = qkv + (size_t)(q0 + l15) * 3072 + h * 64 + lg * 8;
        qf[0] = *(const bf16x8*)(qrow);
        qf[1] = *(const bf16x8*)(qrow + 32);
    }

    for (int i = tid; i < 258; i += 256) sRelF[i] = rel_emb[i * 16 + h];
    const float relC = rel_emb[257 * 16 + h];

    const int tlo = (n >= 15) ? 0 : (15 - n);
    {
        const int src = n - 15 + tlo;
#pragma unroll
        for (int s = 0; s < 2; ++s) {
            int r0 = wv * 16 + s * 8;
            stage8(qkv + (size_t)(src * 64 + r0) * 3072 + 1024 + h * 64, 3072, &sK[0][r0 * 64], lane);
            stage8(vt + (size_t)(h * 64 + r0) * 4096 + src * 64, 4096, &sV[0][r0 * 64], lane);
        }
    }
    asm volatile("s_waitcnt lgkmcnt(0)" ::: "memory");
    __builtin_amdgcn_s_barrier();

    f32x4 oacc[4] = {};                 // O^T (unnormalized): d = dt*16+lg*4+rr, i = l15
    float rsum = 0.f;                   // per-lane partial of sum_j exp(score)

    for (int t = tlo; t < 16; ++t) {
        const int cur = (t - tlo) & 1;
        if (t < 15) {
            const int src = n - 15 + (t + 1);
#pragma unroll
            for (int s = 0; s < 2; ++s) {
                int r0 = wv * 16 + s * 8;
                stage8(qkv + (size_t)(src * 64 + r0) * 3072 + 1024 + h * 64, 3072, &sK[cur ^ 1][r0 * 64], lane);
                stage8(vt + (size_t)(h * 64 + r0) * 4096 + src * 64, 4096, &sV[cur ^ 1][r0 * 64], lane);
            }
            asm volatile("s_waitcnt vmcnt(4)" ::: "memory");
        } else {
            asm volatile("s_waitcnt vmcnt(0)" ::: "memory");
        }
        __builtin_amdgcn_s_barrier();

        const unsigned short* tK = &sK[cur][0];
        const unsigned short* tV = &sV[cur][0];
        const int woff = 15 - t;

        // ---- S^T = K.Q^T : C[j][i], 8 MFMA; lane: j = jt*16+lg*4+rr, i = l15
        f32x4 st[4] = {};
        __builtin_amdgcn_s_setprio(1);
#pragma unroll
        for (int jt = 0; jt < 4; ++jt) {
            bf16x8 kf0 = ldfrag(tK, jt * 16 + l15, lg);
            bf16x8 kf1 = ldfrag(tK, jt * 16 + l15, lg + 4);
            st[jt] = __builtin_amdgcn_mfma_f32_16x16x32_bf16(kf0, qf[0], st[jt], 0, 0, 0);
            st[jt] = __builtin_amdgcn_mfma_f32_16x16x32_bf16(kf1, qf[1], st[jt], 0, 0, 0);
        }
        __builtin_amdgcn_s_setprio(0);

        // ---- bias + exp (no max-subtraction), pack into PV B-fragments
        unsigned pk0[4], pk1[4];
        if (woff >= 5) {
#pragma unroll
            for (int jt = 0; jt < 4; ++jt) {
                float p0 = __expf(st[jt][0] * 0.125f + relC);
                float p1 = __expf(st[jt][1] * 0.125f + relC);
                float p2 = __expf(st[jt][2] * 0.125f + relC);
                float p3 = __expf(st[jt][3] * 0.125f + relC);
                rsum += (p0 + p1) + (p2 + p3);
                pk0[jt] = cvt_pk_bf16(p0, p1);
                pk1[jt] = cvt_pk_bf16(p2, p3);
            }
        } else if (woff > 0) {
#pragma unroll
            for (int jt = 0; jt < 4; ++jt) {
                float p[4];
#pragma unroll
                for (int rr = 0; rr < 4; ++rr) {
                    int j = jt * 16 + lg * 4 + rr;
                    int relid = min(woff * 64 + iq - j, 256) + 1;
                    p[rr] = __expf(st[jt][rr] * 0.125f + sRelF[relid]);
                    rsum += p[rr];
                }
                pk0[jt] = cvt_pk_bf16(p[0], p[1]);
                pk1[jt] = cvt_pk_bf16(p[2], p[3]);
            }
        } else {
#pragma unroll
            for (int jt = 0; jt < 4; ++jt) {
                float p[4];
#pragma unroll
                for (int rr = 0; rr < 4; ++rr) {
                    int j = jt * 16 + lg * 4 + rr;
                    p[rr] = (j <= iq) ? __expf(st[jt][rr] * 0.125f + sRelF[iq - j + 1]) : 0.0f;
                    rsum += p[rr];
                }
                pk0[jt] = cvt_pk_bf16(p[0], p[1]);
                pk1[jt] = cvt_pk_bf16(p[2], p[3]);
            }
        }

        // ---- O^T += V^T.P^T : 16 x mfma 16x16x16 (P stays in registers)
        __builtin_amdgcn_s_setprio(1);
#pragma unroll
        for (int ks = 0; ks < 4; ++ks) {
            union { unsigned u[2]; s16x4 v; } pu;
            pu.u[0] = pk0[ks]; pu.u[1] = pk1[ks];
#pragma unroll
            for (int dt = 0; dt < 4; ++dt) {
                s16x4 vf = ldfrag64(tV, dt * 16 + l15, 2 * ks + (lg >> 1), lg & 1);
                oacc[dt] = mfma16(vf, pu.v, oacc[dt]);
            }
        }
        __builtin_amdgcn_s_setprio(0);
        __builtin_amdgcn_s_barrier();              // buf[cur] reads done before overwrite
    }

    // ---- single end-of-loop row-sum reduction (lanes sharing l15)
    rsum += __shfl_xor(rsum, 16);
    rsum += __shfl_xor(rsum, 32);
    float inv = 1.0f / rsum;

    // ---- epilogue: normalize, transpose via (dead) sK, coalesced store
    unsigned short* sO = &sK[0][0] + wv * 1024;
#pragma unroll
    for (int dt = 0; dt < 4; ++dt)
#pragma unroll
        for (int c = 0; c < 2; ++c) {
            unsigned pr = cvt_pk_bf16(oacc[dt][2 * c] * inv, oacc[dt][2 * c + 1] * inv);
            int d  = dt * 16 + lg * 4 + 2 * c;
            int off = (l15 << 6) + ((((d >> 3) ^ (l15 & 7)) & 7) << 3) + (d & 7);
            *(unsigned*)(sO + off) = pr;
        }
#pragma unroll
    for (int c2 = 0; c2 < 2; ++c2) {
        int ch = lg + 4 * c2;
        bf16x8 ov = ldfrag(sO, l15, ch);
        *(s16x8*)(outp + (size_t)(q0 + l15) * 1024 + h * 64 + ch * 8) = *(const s16x8*)&ov;
    }
}

// ---------- launch ----------
extern "C" void kernel_launch(void* const* d_in, const int* in_sizes, int n_in,
                              void* d_out, int out_size, void* d_ws, size_t ws_size,
                              hipStream_t stream) {
    const float* x    = (const float*)d_in[0];
    const float* Wq   = (const float*)d_in[1];
    const float* Wk   = (const float*)d_in[2];
    const float* Wv   = (const float*)d_in[3];
    const float* Wo   = (const float*)d_in[4];
    const float* rel  = (const float*)d_in[5];
    const float* ln1g = (const float*)d_in[6];
    const float* ln1b = (const float*)d_in[7];
    const float* ln2g = (const float*)d_in[8];
    const float* ln2b = (const float*)d_in[9];
    const float* W1   = (const float*)d_in[10];
    const float* b1   = (const float*)d_in[11];
    const float* W2   = (const float*)d_in[12];
    const float* b2   = (const float*)d_in[13];

    char* ws = (char*)d_ws;
    unsigned short* wqkvT  = (unsigned short*)(ws + 0);          //  8 MB (Wq,Wk,Wv,Wo transposed)
    unsigned short* woT    = wqkvT + 3145728;
    unsigned short* attnb  = (unsigned short*)(ws + 8388608);    //  8 MB
    unsigned short* w1T    = (unsigned short*)(ws + 16777216);   //  8 MB
    unsigned short* hbuf   = (unsigned short*)(ws + 25165824);   //  8 MB
    unsigned short* w2T    = (unsigned short*)(ws + 33554432);   //  8 MB
    float*          x2     = (float*)(ws + 41943040);            // 16 MB
    unsigned short* qkv    = (unsigned short*)(ws + 58720256);   // 24 MB   [dead after attn]
    unsigned short* vt     = (unsigned short*)(ws + 83886080);   //  8 MB   [dead after attn]
    unsigned short* wopart = (unsigned short*)(ws + 58720256);   // 32 MB   (reuses qkv+vt)
    unsigned short* gbuf   = (unsigned short*)(ws + 58720256);   // 32 MB   (after Wo reduce)
    unsigned short* part   = (unsigned short*)(ws + 0);          // 32 MB   (reuses 0..32MB)

    const int smem = 131072;
    hipFuncSetAttribute((const void*)gemm256_kernel<0>, hipFuncAttributeMaxDynamicSharedMemorySize, smem);
    hipFuncSetAttribute((const void*)gemm256_kernel<2>, hipFuncAttributeMaxDynamicSharedMemorySize, smem);
    hipFuncSetAttribute((const void*)gemm256_kernel<4>, hipFuncAttributeMaxDynamicSharedMemorySize, smem);

    dim3 tb(32, 8);
    tcvt4_kernel<<<dim3(32, 32, 4), tb, 0, stream>>>(Wq, Wk, Wv, Wo, wqkvT);
    tcvt_kernel<<<dim3(128, 32), tb, 0, stream>>>(W1, w1T, 1024, 4096);
    tcvt_kernel<<<dim3(32, 128), tb, 0, stream>>>(W2, w2T, 4096, 1024);

    ln_kernel<<<4096, 256, 0, stream>>>(x, ln1g, ln1b, hbuf);

    // QKV: [4096,1024] x [3072,1024]^T -> qkv   (NT=16: K=1024; gm=16, gn=12)
    gemm256_kernel<0><<<192, 512, smem, stream>>>(hbuf, 1024, wqkvT, 1024, qkv,
                                                  nullptr, 3072, 16, 16, 12, 0ULL);

    tvt_kernel<<<dim3(64, 16), 256, 0, stream>>>(qkv, vt);

    attn5_kernel<<<dim3(64, 16), 256, 0, stream>>>(qkv, vt, rel, attnb);

    // Wo projection split-K=4: [4096,1024] x [1024,1024]^T -> 4 partial slabs
    gemm256_kernel<4><<<256, 512, smem, stream>>>(attnb, 1024, woT, 1024, wopart,
                                                  nullptr, 1024, 4, 16, 4, 4194304ULL);
    // fused: x2 = sum(slabs) + x ; hbuf = LN2(x2)
    reduceln_kernel<<<4096, 256, 0, stream>>>(wopart, x, ln2g, ln2b, x2, hbuf);

    // FFN1: [4096,1024] x [4096,1024]^T + b1, gelu -> gbuf
    gemm256_kernel<2><<<256, 512, smem, stream>>>(hbuf, 1024, w1T, 1024, gbuf,
                                                  b1, 4096, 16, 16, 16, 0ULL);

    // FFN2 split-K=4: [4096,4096] x [1024,4096]^T -> 4 bf16 partial slabs
    gemm256_kernel<4><<<256, 512, smem, stream>>>(gbuf, 4096, w2T, 4096, part,
                                                  nullptr, 1024, 16, 16, 4, 4194304ULL);

    // out = sum(slabs) + b2 + x2
    reduce4_kernel<<<4096, 256, 0, stream>>>(part, b2, x2, (float*)d_out);
}

// Round 14
// 220.985 us; speedup vs baseline: 1.4699x; 1.4699x over previous
//
#include <hip/hip_runtime.h>
#include <math.h>

// ---------- types ----------
typedef __bf16 bf16x8 __attribute__((ext_vector_type(8)));   // MFMA A/B fragment (4 VGPRs)
typedef short  s16x4  __attribute__((ext_vector_type(4)));   // 16x16x16 MFMA A/B fragment (2 VGPRs)
typedef float  f32x4  __attribute__((ext_vector_type(4)));   // MFMA C/D fragment
typedef short  s16x8  __attribute__((ext_vector_type(8)));   // raw 16B data movement

__device__ __forceinline__ unsigned short f2bf(float f) {
    unsigned int u = __float_as_uint(f);
    u += 0x7fffu + ((u >> 16) & 1u);   // round-to-nearest-even
    return (unsigned short)(u >> 16);
}

__device__ __forceinline__ unsigned cvt_pk_bf16(float a, float b) {
    unsigned r;
    asm volatile("v_cvt_pk_bf16_f32 %0, %1, %2" : "=v"(r) : "v"(a), "v"(b));
    return r;
}

// 16x16x16 bf16 MFMA via compiler-known builtin (MAI hazard nops inserted; R6 lesson)
__device__ __forceinline__ f32x4 mfma16(s16x4 a, s16x4 b, f32x4 c) {
#if __has_builtin(__builtin_amdgcn_mfma_f32_16x16x16bf16_1k)
    return __builtin_amdgcn_mfma_f32_16x16x16bf16_1k(a, b, c, 0, 0, 0);
#else
    asm volatile("s_nop 3\n\t"
                 "v_mfma_f32_16x16x16_bf16 %0, %1, %2, %0\n\t"
                 "s_nop 7\n\t"
                 "s_nop 7"
                 : "+v"(c) : "v"(a), "v"(b));
    return c;
#endif
}

// exact-equivalent sigmoid form of tanh-gelu: 0.5x(1+tanh(y)) = x * sigmoid(2y)
__device__ __forceinline__ float gelu_tanh(float x) {
    float z = 1.5957691216057308f * (x + 0.044715f * x * x * x);
    return x / (1.0f + __expf(-z));
}

// ---------- transpose + f32->bf16 convert (batched x4) ----------
__global__ __launch_bounds__(256) void tcvt4_kernel(const float* __restrict__ p0,
                                                    const float* __restrict__ p1,
                                                    const float* __restrict__ p2,
                                                    const float* __restrict__ p3,
                                                    unsigned short* __restrict__ out) {
    __shared__ float tile[32][33];
    int z = blockIdx.z;
    const float* in = (z == 0) ? p0 : (z == 1) ? p1 : (z == 2) ? p2 : p3;
    unsigned short* o = out + (size_t)z * 1048576;
    int tx = threadIdx.x, ty = threadIdx.y;           // 32 x 8
    int k0 = blockIdx.y * 32, n0 = blockIdx.x * 32;
#pragma unroll
    for (int s = 0; s < 4; ++s)
        tile[ty + s * 8][tx] = in[(size_t)(k0 + ty + s * 8) * 1024 + n0 + tx];
    __syncthreads();
#pragma unroll
    for (int s = 0; s < 4; ++s)
        o[(size_t)(n0 + ty + s * 8) * 1024 + k0 + tx] = f2bf(tile[tx][ty + s * 8]);
}

// ---------- transpose + convert, generic: in[K][N] f32 -> out[N][K] bf16 ----------
__global__ __launch_bounds__(256) void tcvt_kernel(const float* __restrict__ in,
                                                   unsigned short* __restrict__ out,
                                                   int K, int N) {
    __shared__ float tile[32][33];
    int tx = threadIdx.x, ty = threadIdx.y;
    int k0 = blockIdx.y * 32, n0 = blockIdx.x * 32;
#pragma unroll
    for (int s = 0; s < 4; ++s)
        tile[ty + s * 8][tx] = in[(size_t)(k0 + ty + s * 8) * N + n0 + tx];
    __syncthreads();
#pragma unroll
    for (int s = 0; s < 4; ++s)
        out[(size_t)(n0 + ty + s * 8) * K + k0 + tx] = f2bf(tile[tx][ty + s * 8]);
}

// ---------- layernorm: x[L][1024] f32 -> out bf16 ----------
__global__ __launch_bounds__(256) void ln_kernel(const float* __restrict__ x,
                                                 const float* __restrict__ g,
                                                 const float* __restrict__ b,
                                                 unsigned short* __restrict__ out) {
    int row = blockIdx.x;
    int tid = threadIdx.x;
    float4 v = ((const float4*)(x + (size_t)row * 1024))[tid];
    float s  = v.x + v.y + v.z + v.w;
    float ss = v.x * v.x + v.y * v.y + v.z * v.z + v.w * v.w;
#pragma unroll
    for (int o = 32; o > 0; o >>= 1) { s += __shfl_down(s, o); ss += __shfl_down(ss, o); }
    __shared__ float red[8];
    if ((tid & 63) == 0) { red[(tid >> 6) * 2] = s; red[(tid >> 6) * 2 + 1] = ss; }
    __syncthreads();
    s  = red[0] + red[2] + red[4] + red[6];
    ss = red[1] + red[3] + red[5] + red[7];
    float mean = s * (1.0f / 1024.0f);
    float var  = ss * (1.0f / 1024.0f) - mean * mean;
    float rs   = rsqrtf(var + 1e-5f);
    float4 gv = ((const float4*)g)[tid];
    float4 bv = ((const float4*)b)[tid];
    ushort4 o4;
    o4.x = f2bf((v.x - mean) * rs * gv.x + bv.x);
    o4.y = f2bf((v.y - mean) * rs * gv.y + bv.y);
    o4.z = f2bf((v.z - mean) * rs * gv.z + bv.z);
    o4.w = f2bf((v.w - mean) * rs * gv.w + bv.w);
    ((ushort4*)(out + (size_t)row * 1024))[tid] = o4;
}

// ---------- fused: x2 = sum(4 slabs)+x ;  hbuf = LN(x2) ----------
__global__ __launch_bounds__(256) void reduceln_kernel(const unsigned short* __restrict__ part,
                                                       const float* __restrict__ xin,
                                                       const float* __restrict__ g,
                                                       const float* __restrict__ b,
                                                       float* __restrict__ x2,
                                                       unsigned short* __restrict__ outbf) {
    int row = blockIdx.x;
    int tid = threadIdx.x;
    int i4  = row * 256 + tid;
    float4 r = ((const float4*)xin)[i4];
    float v0 = r.x, v1 = r.y, v2 = r.z, v3 = r.w;
#pragma unroll
    for (int sl = 0; sl < 4; ++sl) {
        ushort4 u = ((const ushort4*)(part + (size_t)sl * 4194304))[i4];
        v0 += __uint_as_float((unsigned)u.x << 16);
        v1 += __uint_as_float((unsigned)u.y << 16);
        v2 += __uint_as_float((unsigned)u.z << 16);
        v3 += __uint_as_float((unsigned)u.w << 16);
    }
    float4 o; o.x = v0; o.y = v1; o.z = v2; o.w = v3;
    ((float4*)x2)[i4] = o;

    float s  = v0 + v1 + v2 + v3;
    float ss = v0 * v0 + v1 * v1 + v2 * v2 + v3 * v3;
#pragma unroll
    for (int off = 32; off > 0; off >>= 1) { s += __shfl_down(s, off); ss += __shfl_down(ss, off); }
    __shared__ float red[8];
    if ((tid & 63) == 0) { red[(tid >> 6) * 2] = s; red[(tid >> 6) * 2 + 1] = ss; }
    __syncthreads();
    s  = red[0] + red[2] + red[4] + red[6];
    ss = red[1] + red[3] + red[5] + red[7];
    float mean = s * (1.0f / 1024.0f);
    float var  = ss * (1.0f / 1024.0f) - mean * mean;
    float rs   = rsqrtf(var + 1e-5f);
    float4 gv = ((const float4*)g)[tid];
    float4 bv = ((const float4*)b)[tid];
    ushort4 o4;
    o4.x = f2bf((v0 - mean) * rs * gv.x + bv.x);
    o4.y = f2bf((v1 - mean) * rs * gv.y + bv.y);
    o4.z = f2bf((v2 - mean) * rs * gv.z + bv.z);
    o4.w = f2bf((v3 - mean) * rs * gv.w + bv.w);
    ((ushort4*)(outbf + (size_t)row * 1024))[tid] = o4;
}

// ---------- transpose V (bf16): qkv v-part -> vt[1024][4096] ----------
__global__ __launch_bounds__(256) void tvt_kernel(const unsigned short* __restrict__ in,
                                                  unsigned short* __restrict__ out) {
    __shared__ unsigned short tile[64][72];
    int t = threadIdx.x;
    int l0 = blockIdx.x * 64, c0 = blockIdx.y * 64;
    int tr = t >> 3, tc = (t & 7) * 8;
#pragma unroll
    for (int s = 0; s < 2; ++s) {
        int r = tr + s * 32;
        s16x8 v = *(const s16x8*)(in + (size_t)(l0 + r) * 3072 + 2048 + c0 + tc);
        *(s16x8*)(&tile[r][tc]) = v;
    }
    __syncthreads();
#pragma unroll
    for (int s = 0; s < 2; ++s) {
        int c = tr + s * 32;
        s16x8 w;
#pragma unroll
        for (int e = 0; e < 8; ++e) w[e] = (short)tile[tc + e][c];
        *(s16x8*)(out + (size_t)(c0 + c) * 4096 + l0 + tc) = w;
    }
}

// ---------- shared staging helpers (chunk-XOR swizzle, rule 21) ----------
__device__ __forceinline__ void stage8(const unsigned short* __restrict__ src_row0, int ld,
                                       unsigned short* ldsdst, int lane) {
    const int r8 = lane >> 3;
    const int c  = (lane & 7) ^ r8;
    const unsigned short* src = src_row0 + (size_t)r8 * ld + c * 8;
    __builtin_amdgcn_global_load_lds((const __attribute__((address_space(1))) void*)src,
                                     (__attribute__((address_space(3))) void*)ldsdst, 16, 0, 0);
}

__device__ __forceinline__ void stage64(const unsigned short* __restrict__ mat, int ld,
                                        int grow0, int kcol,
                                        unsigned short* lds_tile, int q, int wave, int lane) {
    const int l8 = lane >> 3;
    const int sc = ((lane & 7) ^ l8) << 3;
    const unsigned short* src = mat + (size_t)(grow0 + q * 64 + wave * 8 + l8) * ld + kcol + sc;
    unsigned short* dst = lds_tile + ((q * 64 + wave * 8) << 6);
    __builtin_amdgcn_global_load_lds((const __attribute__((address_space(1))) void*)src,
                                     (__attribute__((address_space(3))) void*)dst, 16, 0, 0);
}

__device__ __forceinline__ bf16x8 ldfrag(const unsigned short* tile, int row, int chunk) {
    return *(const bf16x8*)(tile + (row << 6) + (((chunk ^ row) & 7) << 3));
}

__device__ __forceinline__ s16x4 ldfrag64(const unsigned short* tile, int row, int ch16, int half) {
    return *(const s16x4*)(tile + (row << 6) + (((ch16 ^ row) & 7) << 3) + (half << 2));
}

// ---- inline-asm ds_read (compiler-invisible: enables counted-lgkm pipelining) ----
__device__ __forceinline__ unsigned lds_byte(unsigned base, int row, int chunk) {
    return base + (row << 7) + (((chunk ^ row) & 7) << 4);
}
__device__ __forceinline__ bf16x8 ds_frag(unsigned addr) {
    bf16x8 r;
    asm volatile("ds_read_b128 %0, %1" : "=v"(r) : "v"(addr));
    return r;
}

// ---------- 256x256 pipelined-read 4-phase GEMM (T1..T5 + derived lgkm waits) ----------
// EPI 0: bf16 store; EPI 2: +bias, gelu, bf16; EPI 4: bf16 partial to slab[split]
template <int EPI>
__global__ __launch_bounds__(512, 2) void gemm256_kernel(
        const unsigned short* __restrict__ A, int lda,
        const unsigned short* __restrict__ Bt, int ldb,
        void* __restrict__ Cv, const float* __restrict__ bias,
        int ldc, int NT, int gm, int gn, unsigned long long slab_stride) {
    extern __shared__ unsigned short lds[];
    unsigned short* sA = lds;                  // [2][256*64]
    unsigned short* sB = lds + 2 * 256 * 64;   // [2][256*64]

    const int tid  = threadIdx.x;
    const int wave = tid >> 6, lane = tid & 63;
    const int wr = wave >> 2, wc = wave & 3;       // 2 x 4 wave grid
    const int lg = lane >> 4, l15 = lane & 15;

    const unsigned uA = (unsigned)(size_t)(__attribute__((address_space(3))) void*)sA;
    const unsigned uB = (unsigned)(size_t)(__attribute__((address_space(3))) void*)sB;

    // bijective XCD swizzle (m204)
    const int nwg = gridDim.x;
    const int bid = blockIdx.x;
    const int q8 = nwg >> 3, r8v = nwg & 7;
    const int xcd = bid & 7, loc = bid >> 3;
    const int swz = (xcd < r8v ? xcd * (q8 + 1) : r8v * (q8 + 1) + (xcd - r8v) * q8) + loc;
    const int split = swz / (gm * gn);
    const int rem   = swz % (gm * gn);
    // 2D-banded mapping: 4-wide bcol bands
    const int band = rem / (gm * 4);
    const int r2   = rem % (gm * 4);
    const int brow = (r2 >> 2) << 8;
    const int bcol = (band * 4 + (r2 & 3)) << 8;
    const int kbase = split * (NT << 6);

    f32x4 acc[8][4] = {};
    bf16x8 a0[4][2], a1[4][2], b0[2][2], b1[2][2];

#define STAGE_A(tt, q_, pbuf) stage64(A, lda, brow, kbase + ((tt) << 6), sA + (pbuf) * 16384, (q_), wave, lane)
#define STAGE_B(tt, q_, pbuf) stage64(Bt, ldb, bcol, kbase + ((tt) << 6), sB + (pbuf) * 16384, (q_), wave, lane)

    // prologue: stage t0 -> buf0 (8), t1 -> buf1 (8); wait t0; read a0,b0(t0)
    STAGE_A(0, 0, 0); STAGE_A(0, 1, 0); STAGE_A(0, 2, 0); STAGE_A(0, 3, 0);
    STAGE_B(0, 0, 0); STAGE_B(0, 1, 0); STAGE_B(0, 2, 0); STAGE_B(0, 3, 0);
    STAGE_A(1, 0, 1); STAGE_A(1, 1, 1); STAGE_A(1, 2, 1); STAGE_A(1, 3, 1);
    STAGE_B(1, 0, 1); STAGE_B(1, 1, 1); STAGE_B(1, 2, 1); STAGE_B(1, 3, 1);
    asm volatile("s_waitcnt vmcnt(8)" ::: "memory");   // t0 landed (t1 in flight)
    __builtin_amdgcn_sched_barrier(0);
    __builtin_amdgcn_s_barrier();                      // cross-wave: t0 visible
#pragma unroll
    for (int im = 0; im < 4; ++im)
#pragma unroll
        for (int kk = 0; kk < 2; ++kk)
            a0[im][kk] = ds_frag(lds_byte(uA, wr * 128 + im * 16 + l15, lg + kk * 4));
#pragma unroll
    for (int in = 0; in < 2; ++in)
#pragma unroll
        for (int kk = 0; kk < 2; ++kk)
            b0[in][kk] = ds_frag(lds_byte(uB, wc * 64 + in * 16 + l15, lg + kk * 4));

    for (int t = 0; t < NT; ++t) {
        const int p = t & 1;
        const unsigned uAp = uA + p * 32768, uBp = uB + p * 32768;
        const unsigned uAn = uA + (p ^ 1) * 32768, uBn = uB + (p ^ 1) * 32768;

        // ---- PH1: read a1 | wait a0,b0 done | stage A(t+2,q0,q2->p) | MFMA Q1 = a0*b0
#pragma unroll
        for (int im = 0; im < 4; ++im)
#pragma unroll
            for (int kk = 0; kk < 2; ++kk)
                a1[im][kk] = ds_frag(lds_byte(uAp, wr * 128 + 64 + im * 16 + l15, lg + kk * 4));
        asm volatile("s_waitcnt lgkmcnt(8)" ::: "memory");   // a0,b0 complete; a1 outstanding
        __builtin_amdgcn_sched_barrier(0);
        __builtin_amdgcn_s_barrier();
        if (t + 2 < NT) { STAGE_A(t + 2, 0, p); STAGE_A(t + 2, 2, p); }
        __builtin_amdgcn_s_setprio(1);
#pragma unroll
        for (int kk = 0; kk < 2; ++kk)
#pragma unroll
            for (int im = 0; im < 4; ++im)
#pragma unroll
                for (int in = 0; in < 2; ++in)
                    acc[im][in] = __builtin_amdgcn_mfma_f32_16x16x32_bf16(a0[im][kk], b0[in][kk], acc[im][in], 0, 0, 0);
        __builtin_amdgcn_s_setprio(0);

        // ---- PH2: read b1 | wait a1 | stage A(t+2,q1,q3->p) | MFMA Q2 = a1*b0
#pragma unroll
        for (int in = 0; in < 2; ++in)
#pragma unroll
            for (int kk = 0; kk < 2; ++kk)
                b1[in][kk] = ds_frag(lds_byte(uBp, wc * 64 + 32 + in * 16 + l15, lg + kk * 4));
        asm volatile("s_waitcnt lgkmcnt(4)" ::: "memory");   // a1 complete; b1 outstanding
        __builtin_amdgcn_sched_barrier(0);
        __builtin_amdgcn_s_barrier();
        if (t + 2 < NT) { STAGE_A(t + 2, 1, p); STAGE_A(t + 2, 3, p); }
        __builtin_amdgcn_s_setprio(1);
#pragma unroll
        for (int kk = 0; kk < 2; ++kk)
#pragma unroll
            for (int im = 0; im < 4; ++im)
#pragma unroll
                for (int in = 0; in < 2; ++in)
                    acc[4 + im][in] = __builtin_amdgcn_mfma_f32_16x16x32_bf16(a1[im][kk], b0[in][kk], acc[4 + im][in], 0, 0, 0);
        __builtin_amdgcn_s_setprio(0);

        // ---- PH3: wait b1 | stage B(t+2,q0,q1->p) | MFMA Q3 = a0*b1
        asm volatile("s_waitcnt lgkmcnt(0)" ::: "memory");
        __builtin_amdgcn_sched_barrier(0);
        __builtin_amdgcn_s_barrier();
        if (t + 2 < NT) { STAGE_B(t + 2, 0, p); STAGE_B(t + 2, 1, p); }
        __builtin_amdgcn_s_setprio(1);
#pragma unroll
        for (int kk = 0; kk < 2; ++kk)
#pragma unroll
            for (int im = 0; im < 4; ++im)
#pragma unroll
                for (int in = 0; in < 2; ++in)
                    acc[im][2 + in] = __builtin_amdgcn_mfma_f32_16x16x32_bf16(a0[im][kk], b1[in][kk], acc[im][2 + in], 0, 0, 0);
        __builtin_amdgcn_s_setprio(0);

        // ---- PH4: vmcnt fence | barrier | stage B(t+2,q2,q3->p) | read a0,b0(t+1) | MFMA Q4 = a1*b1
        if (t + 1 < NT) {
            if (t + 2 < NT) asm volatile("s_waitcnt vmcnt(6)" ::: "memory");  // t+1 data landed
            else            asm volatile("s_waitcnt vmcnt(0)" ::: "memory");
            __builtin_amdgcn_sched_barrier(0);
        }
        __builtin_amdgcn_s_barrier();                  // cross-wave: t+1 staging visible
        if (t + 2 < NT) { STAGE_B(t + 2, 2, p); STAGE_B(t + 2, 3, p); }
        if (t + 1 < NT) {
#pragma unroll
            for (int im = 0; im < 4; ++im)
#pragma unroll
                for (int kk = 0; kk < 2; ++kk)
                    a0[im][kk] = ds_frag(lds_byte(uAn, wr * 128 + im * 16 + l15, lg + kk * 4));
#pragma unroll
            for (int in = 0; in < 2; ++in)
#pragma unroll
                for (int kk = 0; kk < 2; ++kk)
                    b0[in][kk] = ds_frag(lds_byte(uBn, wc * 64 + in * 16 + l15, lg + kk * 4));
        }
        __builtin_amdgcn_s_setprio(1);
#pragma unroll
        for (int kk = 0; kk < 2; ++kk)
#pragma unroll
            for (int im = 0; im < 4; ++im)
#pragma unroll
                for (int in = 0; in < 2; ++in)
                    acc[4 + im][2 + in] = __builtin_amdgcn_mfma_f32_16x16x32_bf16(a1[im][kk], b1[in][kk], acc[4 + im][2 + in], 0, 0, 0);
        __builtin_amdgcn_s_setprio(0);
    }
#undef STAGE_A
#undef STAGE_B

#pragma unroll
    for (int mi = 0; mi < 8; ++mi)
#pragma unroll
        for (int ni = 0; ni < 4; ++ni)
#pragma unroll
            for (int rr = 0; rr < 4; ++rr) {
                int row = brow + wr * 128 + mi * 16 + lg * 4 + rr;
                int col = bcol + wc * 64 + ni * 16 + l15;
                float v = acc[mi][ni][rr];
                if (EPI == 0) {
                    ((unsigned short*)Cv)[(size_t)row * ldc + col] = f2bf(v);
                } else if (EPI == 2) {
                    v += bias[col];
                    ((unsigned short*)Cv)[(size_t)row * ldc + col] = f2bf(gelu_tanh(v));
                } else {
                    ((unsigned short*)Cv)[slab_stride * split + (size_t)row * ldc + col] = f2bf(v);
                }
            }
}

// ---------- split-K reduce (final): out = sum(4 slabs) + bias + resid ----------
__global__ __launch_bounds__(256) void reduce4_kernel(const unsigned short* __restrict__ part,
                                                      const float* __restrict__ bias,
                                                      const float* __restrict__ resid,
                                                      float* __restrict__ out) {
    int i4 = blockIdx.x * 256 + threadIdx.x;
    float4 r  = ((const float4*)resid)[i4];
    float4 bb = ((const float4*)bias)[i4 & 255];
    float s0 = r.x + bb.x, s1 = r.y + bb.y, s2 = r.z + bb.z, s3 = r.w + bb.w;
#pragma unroll
    for (int s = 0; s < 4; ++s) {
        ushort4 u = ((const ushort4*)(part + (size_t)s * 4194304))[i4];
        s0 += __uint_as_float((unsigned)u.x << 16);
        s1 += __uint_as_float((unsigned)u.y << 16);
        s2 += __uint_as_float((unsigned)u.z << 16);
        s3 += __uint_as_float((unsigned)u.w << 16);
    }
    float4 o; o.x = s0; o.y = s1; o.z = s2; o.w = s3;
    ((float4*)out)[i4] = o;
}

// ---------- band attention v5: no-max softmax (scores bounded), deferred row-sum ----------
__global__ __launch_bounds__(256, 4) void attn5_kernel(const unsigned short* __restrict__ qkv, // [4096][3072]
                                                       const unsigned short* __restrict__ vt,  // [1024][4096]
                                                       const float* __restrict__ rel_emb,      // [258][16]
                                                       unsigned short* __restrict__ outp) {    // [4096][1024]
    const int lid = blockIdx.y * gridDim.x + blockIdx.x;      // 0..1023
    const int rid = (lid & 7) * 128 + (lid >> 3);             // XCD-contiguous
    const int h   = rid >> 6;
    const int n   = rid & 63;

    const int tid  = threadIdx.x;
    const int wv   = tid >> 6;         // 0..3
    const int lane = tid & 63;
    const int lg   = lane >> 4;
    const int l15  = lane & 15;
    const int iq   = wv * 16 + l15;
    const int q0   = n * 64 + wv * 16;

    __shared__ __align__(16) unsigned short sK[2][4096];
    __shared__ __align__(16) unsigned short sV[2][4096];
    __shared__ float sRelF[258];

    bf16x8 qf[2];
    {
        const unsigned short* qrow = qkv + (size_t)(q0 + l15) * 3072 + h * 64 + lg * 8;
        qf[0] = *(const bf16x8*)(qrow);
        qf[1] = *(const bf16x8*)(qrow + 32);
    }

    for (int i = tid; i < 258; i += 256) sRelF[i] = rel_emb[i * 16 + h];
    const float relC = rel_emb[257 * 16 + h];

    const int tlo = (n >= 15) ? 0 : (15 - n);
    {
        const int src = n - 15 + tlo;
#pragma unroll
        for (int s = 0; s < 2; ++s) {
            int r0 = wv * 16 + s * 8;
            stage8(qkv + (size_t)(src * 64 + r0) * 3072 + 1024 + h * 64, 3072, &sK[0][r0 * 64], lane);
            stage8(vt + (size_t)(h * 64 + r0) * 4096 + src * 64, 4096, &sV[0][r0 * 64], lane);
        }
    }
    asm volatile("s_waitcnt lgkmcnt(0)" ::: "memory");
    __builtin_amdgcn_s_barrier();

    f32x4 oacc[4] = {};                 // O^T (unnormalized): d = dt*16+lg*4+rr, i = l15
    float rsum = 0.f;                   // per-lane partial of sum_j exp(score)

    for (int t = tlo; t < 16; ++t) {
        const int cur = (t - tlo) & 1;
        if (t < 15) {
            const int src = n - 15 + (t + 1);
#pragma unroll
            for (int s = 0; s < 2; ++s) {
                int r0 = wv * 16 + s * 8;
                stage8(qkv + (size_t)(src * 64 + r0) * 3072 + 1024 + h * 64, 3072, &sK[cur ^ 1][r0 * 64], lane);
                stage8(vt + (size_t)(h * 64 + r0) * 4096 + src * 64, 4096, &sV[cur ^ 1][r0 * 64], lane);
            }
            asm volatile("s_waitcnt vmcnt(4)" ::: "memory");
        } else {
            asm volatile("s_waitcnt vmcnt(0)" ::: "memory");
        }
        __builtin_amdgcn_s_barrier();

        const unsigned short* tK = &sK[cur][0];
        const unsigned short* tV = &sV[cur][0];
        const int woff = 15 - t;

        // ---- S^T = K.Q^T : C[j][i], 8 MFMA; lane: j = jt*16+lg*4+rr, i = l15
        f32x4 st[4] = {};
        __builtin_amdgcn_s_setprio(1);
#pragma unroll
        for (int jt = 0; jt < 4; ++jt) {
            bf16x8 kf0 = ldfrag(tK, jt * 16 + l15, lg);
            bf16x8 kf1 = ldfrag(tK, jt * 16 + l15, lg + 4);
            st[jt] = __builtin_amdgcn_mfma_f32_16x16x32_bf16(kf0, qf[0], st[jt], 0, 0, 0);
            st[jt] = __builtin_amdgcn_mfma_f32_16x16x32_bf16(kf1, qf[1], st[jt], 0, 0, 0);
        }
        __builtin_amdgcn_s_setprio(0);

        // ---- bias + exp (no max-subtraction), pack into PV B-fragments
        unsigned pk0[4], pk1[4];
        if (woff >= 5) {
#pragma unroll
            for (int jt = 0; jt < 4; ++jt) {
                float p0 = __expf(st[jt][0] * 0.125f + relC);
                float p1 = __expf(st[jt][1] * 0.125f + relC);
                float p2 = __expf(st[jt][2] * 0.125f + relC);
                float p3 = __expf(st[jt][3] * 0.125f + relC);
                rsum += (p0 + p1) + (p2 + p3);
                pk0[jt] = cvt_pk_bf16(p0, p1);
                pk1[jt] = cvt_pk_bf16(p2, p3);
            }
        } else if (woff > 0) {
#pragma unroll
            for (int jt = 0; jt < 4; ++jt) {
                float p[4];
#pragma unroll
                for (int rr = 0; rr < 4; ++rr) {
                    int j = jt * 16 + lg * 4 + rr;
                    int relid = min(woff * 64 + iq - j, 256) + 1;
                    p[rr] = __expf(st[jt][rr] * 0.125f + sRelF[relid]);
                    rsum += p[rr];
                }
                pk0[jt] = cvt_pk_bf16(p[0], p[1]);
                pk1[jt] = cvt_pk_bf16(p[2], p[3]);
            }
        } else {
#pragma unroll
            for (int jt = 0; jt < 4; ++jt) {
                float p[4];
#pragma unroll
                for (int rr = 0; rr < 4; ++rr) {
                    int j = jt * 16 + lg * 4 + rr;
                    p[rr] = (j <= iq) ? __expf(st[jt][rr] * 0.125f + sRelF[iq - j + 1]) : 0.0f;
                    rsum += p[rr];
                }
                pk0[jt] = cvt_pk_bf16(p[0], p[1]);
                pk1[jt] = cvt_pk_bf16(p[2], p[3]);
            }
        }

        // ---- O^T += V^T.P^T : 16 x mfma 16x16x16 (P stays in registers)
        __builtin_amdgcn_s_setprio(1);
#pragma unroll
        for (int ks = 0; ks < 4; ++ks) {
            union { unsigned u[2]; s16x4 v; } pu;
            pu.u[0] = pk0[ks]; pu.u[1] = pk1[ks];
#pragma unroll
            for (int dt = 0; dt < 4; ++dt) {
                s16x4 vf = ldfrag64(tV, dt * 16 + l15, 2 * ks + (lg >> 1), lg & 1);
                oacc[dt] = mfma16(vf, pu.v, oacc[dt]);
            }
        }
        __builtin_amdgcn_s_setprio(0);
        __builtin_amdgcn_s_barrier();              // buf[cur] reads done before overwrite
    }

    // ---- single end-of-loop row-sum reduction (lanes sharing l15)
    rsum += __shfl_xor(rsum, 16);
    rsum += __shfl_xor(rsum, 32);
    float inv = 1.0f / rsum;

    // ---- epilogue: normalize, transpose via (dead) sK, coalesced store
    unsigned short* sO = &sK[0][0] + wv * 1024;
#pragma unroll
    for (int dt = 0; dt < 4; ++dt)
#pragma unroll
        for (int c = 0; c < 2; ++c) {
            unsigned pr = cvt_pk_bf16(oacc[dt][2 * c] * inv, oacc[dt][2 * c + 1] * inv);
            int d  = dt * 16 + lg * 4 + 2 * c;
            int off = (l15 << 6) + ((((d >> 3) ^ (l15 & 7)) & 7) << 3) + (d & 7);
            *(unsigned*)(sO + off) = pr;
        }
#pragma unroll
    for (int c2 = 0; c2 < 2; ++c2) {
        int ch = lg + 4 * c2;
        bf16x8 ov = ldfrag(sO, l15, ch);
        *(s16x8*)(outp + (size_t)(q0 + l15) * 1024 + h * 64 + ch * 8) = *(const s16x8*)&ov;
    }
}

// ---------- launch ----------
extern "C" void kernel_launch(void* const* d_in, const int* in_sizes, int n_in,
                              void* d_out, int out_size, void* d_ws, size_t ws_size,
                              hipStream_t stream) {
    const float* x    = (const float*)d_in[0];
    const float* Wq   = (const float*)d_in[1];
    const float* Wk   = (const float*)d_in[2];
    const float* Wv   = (const float*)d_in[3];
    const float* Wo   = (const float*)d_in[4];
    const float* rel  = (const float*)d_in[5];
    const float* ln1g = (const float*)d_in[6];
    const float* ln1b = (const float*)d_in[7];
    const float* ln2g = (const float*)d_in[8];
    const float* ln2b = (const float*)d_in[9];
    const float* W1   = (const float*)d_in[10];
    const float* b1   = (const float*)d_in[11];
    const float* W2   = (const float*)d_in[12];
    const float* b2   = (const float*)d_in[13];

    char* ws = (char*)d_ws;
    unsigned short* wqkvT  = (unsigned short*)(ws + 0);          //  8 MB (Wq,Wk,Wv,Wo transposed)
    unsigned short* woT    = wqkvT + 3145728;
    unsigned short* attnb  = (unsigned short*)(ws + 8388608);    //  8 MB
    unsigned short* w1T    = (unsigned short*)(ws + 16777216);   //  8 MB
    unsigned short* hbuf   = (unsigned short*)(ws + 25165824);   //  8 MB
    unsigned short* w2T    = (unsigned short*)(ws + 33554432);   //  8 MB
    float*          x2     = (float*)(ws + 41943040);            // 16 MB
    unsigned short* qkv    = (unsigned short*)(ws + 58720256);   // 24 MB   [dead after attn]
    unsigned short* vt     = (unsigned short*)(ws + 83886080);   //  8 MB   [dead after attn]
    unsigned short* wopart = (unsigned short*)(ws + 58720256);   // 32 MB   (reuses qkv+vt)
    unsigned short* gbuf   = (unsigned short*)(ws + 58720256);   // 32 MB   (after Wo reduce)
    unsigned short* part   = (unsigned short*)(ws + 0);          // 32 MB   (reuses 0..32MB)

    const int smem = 131072;
    hipFuncSetAttribute((const void*)gemm256_kernel<0>, hipFuncAttributeMaxDynamicSharedMemorySize, smem);
    hipFuncSetAttribute((const void*)gemm256_kernel<2>, hipFuncAttributeMaxDynamicSharedMemorySize, smem);
    hipFuncSetAttribute((const void*)gemm256_kernel<4>, hipFuncAttributeMaxDynamicSharedMemorySize, smem);

    dim3 tb(32, 8);
    tcvt4_kernel<<<dim3(32, 32, 4), tb, 0, stream>>>(Wq, Wk, Wv, Wo, wqkvT);
    tcvt_kernel<<<dim3(128, 32), tb, 0, stream>>>(W1, w1T, 1024, 4096);
    tcvt_kernel<<<dim3(32, 128), tb, 0, stream>>>(W2, w2T, 4096, 1024);

    ln_kernel<<<4096, 256, 0, stream>>>(x, ln1g, ln1b, hbuf);

    // QKV: [4096,1024] x [3072,1024]^T -> qkv
    gemm256_kernel<0><<<192, 512, smem, stream>>>(hbuf, 1024, wqkvT, 1024, qkv,
                                                  nullptr, 3072, 16, 16, 12, 0ULL);

    tvt_kernel<<<dim3(64, 16), 256, 0, stream>>>(qkv, vt);

    attn5_kernel<<<dim3(64, 16), 256, 0, stream>>>(qkv, vt, rel, attnb);

    // Wo projection split-K=4: [4096,1024] x [1024,1024]^T -> 4 partial slabs
    gemm256_kernel<4><<<256, 512, smem, stream>>>(attnb, 1024, woT, 1024, wopart,
                                                  nullptr, 1024, 4, 16, 4, 4194304ULL);
    // fused: x2 = sum(slabs) + x ; hbuf = LN2(x2)
    reduceln_kernel<<<4096, 256, 0, stream>>>(wopart, x, ln2g, ln2b, x2, hbuf);

    // FFN1: [4096,1024] x [4096,1024]^T + b1, gelu -> gbuf
    gemm256_kernel<2><<<256, 512, smem, stream>>>(hbuf, 1024, w1T, 1024, gbuf,
                                                  b1, 4096, 16, 16, 16, 0ULL);

    // FFN2 split-K=4: [4096,4096] x [1024,4096]^T -> 4 bf16 partial slabs
    gemm256_kernel<4><<<256, 512, smem, stream>>>(gbuf, 4096, w2T, 4096, part,
                                                  nullptr, 1024, 16, 16, 4, 4194304ULL);

    // out = sum(slabs) + b2 + x2
    reduce4_kernel<<<4096, 256, 0, stream>>>(part, b2, x2, (float*)d_out);
}